// Round 9
// baseline (245.052 us; speedup 1.0000x reference)
//
#include <hip/hip_runtime.h>

// B=8, N=196, C=512, NC=10, H=8, HD=64, SCALE=0.125
//
// Pipeline (all matmuls bf16 MFMA 16x16x32, fp32 accum):
//   pre:       x,anchors -> bf16;  Wqk,Wqk2,Wv,Wproj -> bf16 TRANSPOSED [n][k]
//   proj_combo: z=0: {xq,xq2,xv} = xb @ {Wqk,Wqk2,Wv}^T staging As ONCE;
//              z=1: {aq,aq2}    = ab @ {Wqk,Wqk2}^T
//   rv:        rvt[bch][it][64dd][64i] = (relu(+S*k2@q2^T) @ v)^T
//              (swapped-QK; kb AND q-fragments direct global->reg — A-operand is
//               wave-uniform, L1-broadcast; LDS only Vt+Ss = 18,432B, no DMA drains)
//   attn:      left = relu(-S*q@k^T) -> d_out; P bf16
//              (swapped-QK; qb, K-fragments, rv tiles ALL direct global->reg;
//               LDS only Ss = 9,216B; jt=3 pad rows via compile-time guard)
//   reduce:    out1 = sum_c w * P (bf16). R7 lesson: per-block __threadfence
//              (buffer_wbl2/inv) serializes the chip — keep this a separate kernel.
//   final:     out = out1 @ Wproj + bproj (f32)
#define OFF_XB     0u          // x bf16        1,605,632
#define OFF_AB     1605632u    // anchors bf16  2,007,040
#define OFF_WQKT   3612672u    // 512x512 bf16 T  524,288
#define OFF_WQK2T  4136960u
#define OFF_WVT    4661248u
#define OFF_WPROJT 5185536u
#define OFF_XQ     5709824u    // 1,605,632
#define OFF_XQ2    7315456u
#define OFF_XV     8921088u
#define OFF_AQ     10526720u   // 2,007,040
#define OFF_AQ2    12533760u
#define OFF_RVT    14540800u   // 640*4*64*64*2 = 20,971,520
#define OFF_OUT1   35512320u   // 1568*512 bf16 = 1,605,632
#define OFF_P      37117952u   // 640*196*64 bf16 = 16,056,320 -> end 53,174,272

typedef __attribute__((ext_vector_type(8))) short bf16x8;
typedef __attribute__((ext_vector_type(4))) float f32x4;
#define MFMA(a, b, c) __builtin_amdgcn_mfma_f32_16x16x32_bf16((a), (b), (c), 0, 0, 0)

__device__ __forceinline__ unsigned short f2bf(float x) {
  unsigned u = __builtin_bit_cast(unsigned, x);
  u += 0x7fffu + ((u >> 16) & 1u);
  return (unsigned short)(u >> 16);
}
__device__ __forceinline__ float bf2f(unsigned short s) {
  return __builtin_bit_cast(float, ((unsigned)s) << 16);
}

__device__ __forceinline__ void gl_lds16(const void* g, void* l) {
  __builtin_amdgcn_global_load_lds(
      (const __attribute__((address_space(1))) unsigned int*)g,
      (__attribute__((address_space(3))) unsigned int*)l, 16, 0, 0);
}

// Stage a 64x64 bf16 tile (row stride `stride` shorts) into LDS [64][72] via
// global_load_lds. Rows >= nrows skipped.
__device__ __forceinline__ void stage64(const unsigned short* g0, int stride,
                                        unsigned short (*T)[72], int tid, int nrows) {
  int wv = tid >> 6;
  char* base = (char*)&T[0][0];
#pragma unroll
  for (int i = 0; i < 2; i++) {
    int k = i * 256 + tid;
    int r = k / 9, c = k - r * 9;
    if (r < nrows)
      gl_lds16(g0 + (size_t)r * stride + (c << 3), base + (((i << 2) + wv) << 10));
  }
  if (tid < 64) {
    int k = 512 + tid;
    int r = k / 9, c = k - r * 9;
    if (r < nrows)
      gl_lds16(g0 + (size_t)r * stride + (c << 3), base + 8192);
  }
}

// V-transpose load split: issue global loads early (regs), write LDS late.
__device__ __forceinline__ void vload_T(uint4* va, uint4* vb, const unsigned short* __restrict__ g,
                                        int row0, int nrows, int col0, int tid) {
  int j0 = tid >> 3, d0 = (tid & 7) << 3;
  *va = make_uint4(0, 0, 0, 0);
  *vb = make_uint4(0, 0, 0, 0);
  if (j0 < nrows) *va = *(const uint4*)(g + (size_t)(row0 + j0) * 512 + col0 + d0);
  if (j0 + 32 < nrows) *vb = *(const uint4*)(g + (size_t)(row0 + j0 + 32) * 512 + col0 + d0);
}
__device__ __forceinline__ void vwrite_T(unsigned short T[64][72], uint4 va, uint4 vb, int tid) {
  int j0 = tid >> 3, d0 = (tid & 7) << 3;
  unsigned short s[8];
  *(uint4*)s = va;
#pragma unroll
  for (int u = 0; u < 8; u++) T[d0 + u][j0] = s[u];
  *(uint4*)s = vb;
#pragma unroll
  for (int u = 0; u < 8; u++) T[d0 + u][j0 + 32] = s[u];
}

// ---- pre: bf16 conversions + W transposes ----
__global__ __launch_bounds__(256) void pre_kernel(const float* __restrict__ x, const float* __restrict__ anchors,
                                                  const float* __restrict__ Wqk, const float* __restrict__ Wqk2,
                                                  const float* __restrict__ Wv, const float* __restrict__ Wproj,
                                                  char* __restrict__ ws) {
  int tid = threadIdx.x;
  if (blockIdx.x < 1764) {  // flat convert x (802816) + anchors (1003520) -> XB/AB (contiguous)
    int base = blockIdx.x * 1024 + (tid << 2);
    float4 f = (base < 802816) ? *(const float4*)(x + base)
                               : *(const float4*)(anchors + (base - 802816));
    unsigned short s[4] = {f2bf(f.x), f2bf(f.y), f2bf(f.z), f2bf(f.w)};
    *(uint2*)((unsigned short*)(ws + OFF_XB) + base) = *(uint2*)s;
    return;
  }
  // W transpose tiles: 4 matrices x 64 tiles
  __shared__ __align__(16) unsigned short Ls[64][72];
  int idx = blockIdx.x - 1764;
  int wsel = idx >> 6, t = idx & 63;
  int k0 = (t >> 3) << 6, n0 = (t & 7) << 6;
  const float* W;
  unsigned short* WT;
  switch (wsel) {
    case 0:  W = Wqk;   WT = (unsigned short*)(ws + OFF_WQKT);   break;
    case 1:  W = Wqk2;  WT = (unsigned short*)(ws + OFF_WQK2T);  break;
    case 2:  W = Wv;    WT = (unsigned short*)(ws + OFF_WVT);    break;
    default: W = Wproj; WT = (unsigned short*)(ws + OFF_WPROJT); break;
  }
  {  // load [k][n] tile, convert
    int r = tid >> 2, seg = (tid & 3) << 4;
    const float* p = W + (size_t)(k0 + r) * 512 + n0 + seg;
    float4 f0 = *(const float4*)p, f1 = *(const float4*)(p + 4);
    float4 f2 = *(const float4*)(p + 8), f3 = *(const float4*)(p + 12);
    unsigned short s[16] = {f2bf(f0.x), f2bf(f0.y), f2bf(f0.z), f2bf(f0.w),
                            f2bf(f1.x), f2bf(f1.y), f2bf(f1.z), f2bf(f1.w),
                            f2bf(f2.x), f2bf(f2.y), f2bf(f2.z), f2bf(f2.w),
                            f2bf(f3.x), f2bf(f3.y), f2bf(f3.z), f2bf(f3.w)};
    *(uint4*)&Ls[r][seg] = *(uint4*)s;
    *(uint4*)&Ls[r][seg + 8] = *(uint4*)(s + 8);
  }
  __syncthreads();
  {  // write transposed rows [n][k]
    int r = tid >> 2, seg = (tid & 3) << 4;
    unsigned short s[16];
#pragma unroll
    for (int u = 0; u < 16; u++) s[u] = Ls[seg + u][r];
    unsigned short* dst = WT + (size_t)(n0 + r) * 512 + k0 + seg;
    *(uint4*)dst = *(uint4*)s;
    *(uint4*)(dst + 8) = *(uint4*)(s + 8);
  }
}

// ---- proj_combo: NW outputs sharing one A staging ----
template <int NW>
__device__ __forceinline__ void proj_body(const unsigned short* __restrict__ A,
                                          const unsigned short* W0, const unsigned short* W1,
                                          const unsigned short* W2,
                                          unsigned short* O0, unsigned short* O1, unsigned short* O2,
                                          int M, unsigned short (*As)[72], unsigned short (*Wsh)[72]) {
  int row0 = (int)blockIdx.x << 6;
  if (row0 >= M) return;
  int col0 = (int)blockIdx.y << 6;
  int tid = threadIdx.x;
  int w = tid >> 6, lm = tid & 15, lq = (tid >> 4) & 3;
  const unsigned short* WTs[3] = {W0, W1, W2};
  unsigned short* Os[3] = {O0, O1, O2};
  f32x4 acc[NW][4] = {};
  for (int k0 = 0; k0 < 512; k0 += 64) {
    __syncthreads();
    stage64(A + (size_t)row0 * 512 + k0, 512, As, tid, 64);  // garbage rows past M masked at store
#pragma unroll
    for (int ww = 0; ww < NW; ww++)
      stage64(WTs[ww] + (size_t)col0 * 512 + k0, 512,
              (unsigned short(*)[72])&Wsh[ww << 6], tid, 64);
    __syncthreads();
#pragma unroll
    for (int kk = 0; kk < 2; kk++) {
      bf16x8 af[4];
#pragma unroll
      for (int mi = 0; mi < 4; mi++)
        af[mi] = *(const bf16x8*)&As[(mi << 4) + lm][(kk << 5) + (lq << 3)];
#pragma unroll
      for (int ww = 0; ww < NW; ww++) {
        bf16x8 bf = *(const bf16x8*)&Wsh[(ww << 6) + (w << 4) + lm][(kk << 5) + (lq << 3)];
#pragma unroll
        for (int mi = 0; mi < 4; mi++) acc[ww][mi] = MFMA(af[mi], bf, acc[ww][mi]);
      }
    }
  }
  int ncol = col0 + (w << 4) + lm;
#pragma unroll
  for (int ww = 0; ww < NW; ww++)
#pragma unroll
    for (int mi = 0; mi < 4; mi++)
#pragma unroll
      for (int r2 = 0; r2 < 4; r2++) {
        int row = row0 + (mi << 4) + (lq << 2) + r2;
        if (row < M)
          Os[ww][(size_t)row * 512 + ncol] = f2bf(acc[ww][mi][r2]);
      }
}

__global__ __launch_bounds__(256) void proj_combo(char* __restrict__ ws) {
  __shared__ __align__(16) unsigned short As[64][72];
  __shared__ __align__(16) unsigned short Wsh[192][72];
  const unsigned short* xb = (const unsigned short*)(ws + OFF_XB);
  const unsigned short* ab = (const unsigned short*)(ws + OFF_AB);
  const unsigned short* wqkt  = (const unsigned short*)(ws + OFF_WQKT);
  const unsigned short* wqk2t = (const unsigned short*)(ws + OFF_WQK2T);
  const unsigned short* wvt   = (const unsigned short*)(ws + OFF_WVT);
  if (blockIdx.z == 0)
    proj_body<3>(xb, wqkt, wqk2t, wvt,
                 (unsigned short*)(ws + OFF_XQ), (unsigned short*)(ws + OFF_XQ2),
                 (unsigned short*)(ws + OFF_XV), 1568, As, Wsh);
  else
    proj_body<2>(ab, wqkt, wqk2t, nullptr,
                 (unsigned short*)(ws + OFF_AQ), (unsigned short*)(ws + OFF_AQ2),
                 nullptr, 1960, As, Wsh);
}

// ---- final GEMM: out[1568,512] = out1 @ WprojT^T + bias (f32) ----
__global__ __launch_bounds__(256) void final_gemm(const unsigned short* __restrict__ out1,
                                                  const unsigned short* __restrict__ WT,
                                                  const float* __restrict__ bias, float* __restrict__ out) {
  __shared__ __align__(16) unsigned short As[64][72];
  __shared__ __align__(16) unsigned short Ws[64][72];
  int row0 = (int)blockIdx.x << 6;
  int col0 = (int)blockIdx.y << 6;
  int tid = threadIdx.x;
  int w = tid >> 6, lm = tid & 15, lq = (tid >> 4) & 3;
  f32x4 acc[4] = {};
  for (int k0 = 0; k0 < 512; k0 += 64) {
    __syncthreads();
    stage64(out1 + (size_t)row0 * 512 + k0, 512, As, tid, 64);
    stage64(WT + (size_t)col0 * 512 + k0, 512, Ws, tid, 64);
    __syncthreads();
#pragma unroll
    for (int kk = 0; kk < 2; kk++) {
      bf16x8 bf = *(const bf16x8*)&Ws[(w << 4) + lm][(kk << 5) + (lq << 3)];
#pragma unroll
      for (int mi = 0; mi < 4; mi++) {
        bf16x8 af = *(const bf16x8*)&As[(mi << 4) + lm][(kk << 5) + (lq << 3)];
        acc[mi] = MFMA(af, bf, acc[mi]);
      }
    }
  }
  int ncol = col0 + (w << 4) + lm;
  float bv = bias[ncol];
#pragma unroll
  for (int mi = 0; mi < 4; mi++)
#pragma unroll
    for (int r2 = 0; r2 < 4; r2++) {
      int row = row0 + (mi << 4) + (lq << 2) + r2;
      if (row < 1568)
        out[(size_t)row * 512 + ncol] = acc[mi][r2] + bv;
    }
}

// ---- rv: rvt[bch][it][dd][i=64] = (relu(0.125 * k2 @ q2^T) @ v)^T ----
// Swapped QK. kb AND q-fragments direct global->reg (A-operand wave-uniform, L1
// broadcast; jt=3's tail rows read harmless in-ws garbage, S cols x Vt=0 as before).
// LDS = Vt+Ss (18,432B). XCD-grouped swizzle by (b,h).
__global__ __launch_bounds__(256) void rv_mfma(char* __restrict__ ws) {
  const unsigned short* xq2 = (const unsigned short*)(ws + OFF_XQ2);
  const unsigned short* aq2 = (const unsigned short*)(ws + OFF_AQ2);
  const unsigned short* xv  = (const unsigned short*)(ws + OFF_XV);
  unsigned short* rvt       = (unsigned short*)(ws + OFF_RVT);
  __shared__ __align__(16) unsigned short Vt[64][72];  // Vt[dd][j], zero-padded
  __shared__ __align__(16) unsigned short Ss[64][72];  // S[i][j]
  // d%8 ~ XCD; wk chunks of 320 works stay on one XCD; wk = (bh*10+c)*4 + it
  int d = blockIdx.x;
  int wk = ((d & 7) * 320) + (d >> 3);
  int it = wk & 3;
  int g = wk >> 2;
  int bh = g / 10, c = g - bh * 10;
  int b = bh >> 3, h = bh & 7;
  int bch = (b * 10 + c) * 8 + h;
  int i0 = it << 6;
  int tid = threadIdx.x;
  int w = tid >> 6, lm = tid & 15, lq = (tid >> 4) & 3;
  int iglob = i0 + (w << 4) + lm;

  // kb direct from global; zero for invalid anchor rows (preserves rvt zero-pad invariant)
  bf16x8 kb[2] = {};
  if (iglob < 196) {
    const unsigned short* kp = aq2 + (size_t)(c * 196 + iglob) * 512 + (h << 6) + (lq << 3);
    kb[0] = *(const bf16x8*)kp;
    kb[1] = *(const bf16x8*)(kp + 32);
  }
  uint4 va, vb;
  vload_T(&va, &vb, xv, b * 196, 64, h << 6, tid);
  const unsigned short* qrow = xq2 + (size_t)(b * 196) * 512 + (h << 6) + (lq << 3);

  f32x4 acc[4] = {};
#pragma unroll
  for (int jt = 0; jt < 4; jt++) {
    int j0 = jt << 6;
    __syncthreads();  // prev PV done with Ss/Vt (jt=0: no-op)
    vwrite_T(Vt, va, vb, tid);
    // QK^T swapped: D[m=j][n=i]; q-fragments direct per-lane (rows j0+mj*16+lm)
    f32x4 s[4];
#pragma unroll
    for (int mj = 0; mj < 4; mj++) {
      const unsigned short* qp = qrow + (size_t)(j0 + (mj << 4) + lm) * 512;
      bf16x8 q0 = *(const bf16x8*)qp;
      bf16x8 q1 = *(const bf16x8*)(qp + 32);
      s[mj] = MFMA(q0, kb[0], (f32x4){});
      s[mj] = MFMA(q1, kb[1], s[mj]);
    }
#pragma unroll
    for (int mj = 0; mj < 4; mj++) {  // Ss[i = w*16+lm][j runs of 4]
      unsigned short u[4] = {f2bf(fmaxf(0.125f * s[mj][0], 0.f)), f2bf(fmaxf(0.125f * s[mj][1], 0.f)),
                             f2bf(fmaxf(0.125f * s[mj][2], 0.f)), f2bf(fmaxf(0.125f * s[mj][3], 0.f))};
      *(uint2*)&Ss[(w << 4) + lm][(mj << 4) + (lq << 2)] = *(uint2*)u;
    }
    if (jt < 3) vload_T(&va, &vb, xv, b * 196 + j0 + 64, min(64, 196 - j0 - 64), h << 6, tid);
    __syncthreads();
    // PV: acc[mi] = R[i][dd]
#pragma unroll
    for (int kk = 0; kk < 2; kk++) {
      bf16x8 bf = *(const bf16x8*)&Vt[(w << 4) + lm][(kk << 5) + (lq << 3)];
#pragma unroll
      for (int mi = 0; mi < 4; mi++) {
        bf16x8 af = *(const bf16x8*)&Ss[(mi << 4) + lm][(kk << 5) + (lq << 3)];
        acc[mi] = MFMA(af, bf, acc[mi]);
      }
    }
  }
  __syncthreads();
#pragma unroll
  for (int mi = 0; mi < 4; mi++) {  // transpose: Ss[dd][i runs of 4] (vectorized)
    unsigned short u[4] = {f2bf(acc[mi][0]), f2bf(acc[mi][1]), f2bf(acc[mi][2]), f2bf(acc[mi][3])};
    *(uint2*)&Ss[(w << 4) + lm][(mi << 4) + (lq << 2)] = *(uint2*)u;
  }
  __syncthreads();
  {  // rvt block [bch*4+it][dd][64]; rows i>=196 are zeros (kb zeroed)
    int dd = tid >> 2, seg = (tid & 3) << 4;
    unsigned short* dst = rvt + ((size_t)(bch * 4 + it) * 64 + dd) * 64 + seg;
    *(uint4*)dst = *(uint4*)&Ss[dd][seg];
    *(uint4*)(dst + 8) = *(uint4*)&Ss[dd][seg + 8];
  }
}

// ---- attn: left = relu(-0.125*q@k^T) (cached f32x4); P = left @ rv (bf16) ----
// Swapped QK; qb, K-fragments and rv tiles ALL direct global->reg. LDS = Ss only
// (9,216B). jt=3 pad rows (>=196) zeroed via guard (compile-time-free for jt<3).
__global__ __launch_bounds__(256) void attn_mfma(char* __restrict__ ws, float* __restrict__ left,
                                                 unsigned short* __restrict__ P) {
  const unsigned short* xq  = (const unsigned short*)(ws + OFF_XQ);
  const unsigned short* aq  = (const unsigned short*)(ws + OFF_AQ);
  const unsigned short* rvt = (const unsigned short*)(ws + OFF_RVT);
  __shared__ __align__(16) unsigned short Ss[64][72];  // S[i][j]
  int d = blockIdx.x;
  int wk = ((d & 7) * 320) + (d >> 3);
  int i0 = (wk & 3) << 6;
  int g = wk >> 2;                 // g = c*64 + bh
  int c = g >> 6;
  int bh = g & 63;
  int b = bh >> 3, h = bh & 7;
  int bch = (b * 10 + c) * 8 + h;
  int tid = threadIdx.x;
  int w = tid >> 6, lm = tid & 15, lq = (tid >> 4) & 3;
  int iglob = i0 + (w << 4) + lm;

  // qb direct from global (lane's own row; garbage rows ok - stores masked; stays in ws)
  bf16x8 qb[2];
  {
    const unsigned short* qp = xq + (size_t)(b * 196 + iglob) * 512 + (h << 6) + (lq << 3);
    qb[0] = *(const bf16x8*)qp;
    qb[1] = *(const bf16x8*)(qp + 32);
  }
  const unsigned short* krow = aq + (size_t)(c * 196) * 512 + (h << 6) + (lq << 3);
  // rv fragment prefetch for t=0 (jt=3)
  const unsigned short* rbase = rvt + (size_t)bch * 16384 + (((w << 4) + lm) << 6) + (lq << 3);
  bf16x8 rv0 = *(const bf16x8*)(rbase + 3 * 4096);
  bf16x8 rv1 = *(const bf16x8*)(rbase + 3 * 4096 + 32);

  f32x4 acc[4] = {};
  size_t lbase = (size_t)bch * (196 * 196);
  // jt order {3,0,1,2} kept (same accumulation order as verified kernel).
#pragma unroll
  for (int t = 0; t < 4; t++) {
    int jt = (t == 0) ? 3 : t - 1;
    int j0 = jt << 6;
    __syncthreads();  // prev PV done with Ss (t=0: no-op)
    // QK^T swapped: D[m=j][n=i]; K-fragments direct per-lane, zero past row 196
    f32x4 s[4];
#pragma unroll
    for (int mj = 0; mj < 4; mj++) {
      int jrow = j0 + (mj << 4) + lm;
      bf16x8 k0 = {}, k1 = {};
      if (jrow < 196) {  // provably true for jt<3 (guard folds away)
        const unsigned short* kp = krow + (size_t)jrow * 512;
        k0 = *(const bf16x8*)kp;
        k1 = *(const bf16x8*)(kp + 32);
      }
      s[mj] = MFMA(k0, qb[0], (f32x4){});
      s[mj] = MFMA(k1, qb[1], s[mj]);
    }
#pragma unroll
    for (int mj = 0; mj < 4; mj++) {
      f32x4 lv;
      lv[0] = fmaxf(-0.125f * s[mj][0], 0.f);
      lv[1] = fmaxf(-0.125f * s[mj][1], 0.f);
      lv[2] = fmaxf(-0.125f * s[mj][2], 0.f);
      lv[3] = fmaxf(-0.125f * s[mj][3], 0.f);
      int jloc = (mj << 4) + (lq << 2);
      if (iglob < 196 && j0 + jloc < 196)   // runs never straddle 196 (196%4==0)
        *(f32x4*)&left[lbase + (size_t)iglob * 196 + j0 + jloc] = lv;
      unsigned short u[4] = {f2bf(lv[0]), f2bf(lv[1]), f2bf(lv[2]), f2bf(lv[3])};
      *(uint2*)&Ss[(w << 4) + lm][jloc] = *(uint2*)u;
    }
    __syncthreads();
    bf16x8 cur0 = rv0, cur1 = rv1;
    if (t < 3) {  // prefetch next rv tile (jt = t), consumed next iteration
      rv0 = *(const bf16x8*)(rbase + t * 4096);
      rv1 = *(const bf16x8*)(rbase + t * 4096 + 32);
    }
    // PV: acc[mi] = P[i][dd]
#pragma unroll
    for (int kk = 0; kk < 2; kk++) {
      bf16x8 bf = (kk == 0) ? cur0 : cur1;
#pragma unroll
      for (int mi = 0; mi < 4; mi++) {
        bf16x8 af = *(const bf16x8*)&Ss[(mi << 4) + lm][(kk << 5) + (lq << 3)];
        acc[mi] = MFMA(af, bf, acc[mi]);
      }
    }
  }
  __syncthreads();
#pragma unroll
  for (int mi = 0; mi < 4; mi++)   // P tile transpose into Ss[i][dd]
#pragma unroll
    for (int r = 0; r < 4; r++)
      Ss[(mi << 4) + (lq << 2) + r][(w << 4) + lm] = f2bf(acc[mi][r]);
  __syncthreads();
  {
    int row = tid >> 2, seg = (tid & 3) << 4;
    if (i0 + row < 196) {
      unsigned short* dst = P + ((size_t)(bh * 10 + c) * 196 + i0 + row) * 64 + seg;
      *(uint4*)dst = *(uint4*)&Ss[row][seg];
      *(uint4*)(dst + 8) = *(uint4*)&Ss[row][seg + 8];
    }
  }
}

// ---- out1[bh][n][dd] = sum_c weights[bh,c] * P[bh][c][n][dd]  (bf16 out) ----
__global__ __launch_bounds__(256) void reduce_out1(const unsigned short* __restrict__ P,
                                                   const float* __restrict__ weights,
                                                   unsigned short* __restrict__ out1) {
  int t = blockIdx.x * 256 + threadIdx.x;
  int base = t << 2;
  int bh = base / 12544;
  int rem = base - bh * 12544;
  const float* wrow = weights + bh * 10;
  float a0 = 0.f, a1 = 0.f, a2 = 0.f, a3 = 0.f;
#pragma unroll
  for (int c = 0; c < 10; c++) {
    float wc = wrow[c];
    const unsigned short* p = P + ((size_t)(bh * 10 + c)) * 12544 + rem;
    ushort4 u = *(const ushort4*)p;
    a0 = fmaf(wc, bf2f(u.x), a0);
    a1 = fmaf(wc, bf2f(u.y), a1);
    a2 = fmaf(wc, bf2f(u.z), a2);
    a3 = fmaf(wc, bf2f(u.w), a3);
  }
  unsigned short s[4] = {f2bf(a0), f2bf(a1), f2bf(a2), f2bf(a3)};
  *(uint2*)&out1[base] = *(uint2*)s;
}

extern "C" void kernel_launch(void* const* d_in, const int* in_sizes, int n_in,
                              void* d_out, int out_size, void* d_ws, size_t ws_size,
                              hipStream_t stream) {
  (void)in_sizes; (void)n_in; (void)out_size; (void)ws_size;
  const float* x       = (const float*)d_in[0];
  const float* anchors = (const float*)d_in[1];
  const float* weights = (const float*)d_in[2];
  const float* Wqk     = (const float*)d_in[3];
  const float* Wqk2    = (const float*)d_in[4];
  const float* Wv      = (const float*)d_in[5];
  const float* Wproj   = (const float*)d_in[6];
  const float* bproj   = (const float*)d_in[7];
  char* ws = (char*)d_ws;
  float* out  = (float*)d_out;
  float* left = out + 802816;

  dim3 blk(256);
  pre_kernel<<<dim3(2020), blk, 0, stream>>>(x, anchors, Wqk, Wqk2, Wv, Wproj, ws);
  proj_combo<<<dim3(31, 8, 2), blk, 0, stream>>>(ws);
  rv_mfma<<<dim3(2560), blk, 0, stream>>>(ws);
  attn_mfma<<<dim3(2560), blk, 0, stream>>>(ws, left, (unsigned short*)(ws + OFF_P));
  reduce_out1<<<dim3(784), blk, 0, stream>>>((const unsigned short*)(ws + OFF_P), weights,
                                             (unsigned short*)(ws + OFF_OUT1));
  final_gemm<<<dim3(25, 8), blk, 0, stream>>>((const unsigned short*)(ws + OFF_OUT1),
                                              (const unsigned short*)(ws + OFF_WPROJT), bproj, out);
}

// Round 10
// 206.284 us; speedup vs baseline: 1.1879x; 1.1879x over previous
//
#include <hip/hip_runtime.h>

// B=8, N=196, C=512, NC=10, H=8, HD=64, SCALE=0.125
//
// Pipeline (all matmuls bf16 MFMA 16x16x32, fp32 accum):
//   pre:       Wqk,Wqk2,Wv,Wproj -> bf16 TRANSPOSED [n][k]  (256 blocks only)
//   proj_combo: z=0: {xq,xq2,xv} = x @ {Wqk,Wqk2,Wv}^T; z=1: {aq,aq2} = anchors @ ...
//              A-tiles converted fp32->bf16 DURING staging (pre's convert pass removed)
//   rv:        rvt[bch][it][64dd][64i] = (relu(+S*k2@q2^T) @ v)^T  (R8 structure:
//              staged Qs DMA w/ prefetch, kb direct; Vt XOR-swizzled vs 8-way conflicts)
//   attn:      left = relu(-S*q@k^T) -> d_out (fp32 cached f32x4); P bf16
//              (R8 structure: staged Ks DMA w/ prefetch, qb + rv direct global->reg)
//   reduce:    out1 = sum_c w * P (bf16). R7 lesson: per-block __threadfence
//              (buffer_wbl2/inv) serializes the chip — keep separate kernel.
//   final:     out = out1 @ Wproj + bproj (f32)
// R9 lesson: direct per-lane loads feeding the next MFMA put L2 latency on the
// critical path; staged DMA + one-iteration prefetch hides it. Direct loads only
// for operands loaded once per block (qb/kb/rv fragments).
#define OFF_XB     0u          // (unused now, kept for layout stability)
#define OFF_AB     1605632u
#define OFF_WQKT   3612672u    // 512x512 bf16 T  524,288
#define OFF_WQK2T  4136960u
#define OFF_WVT    4661248u
#define OFF_WPROJT 5185536u
#define OFF_XQ     5709824u    // 1,605,632
#define OFF_XQ2    7315456u
#define OFF_XV     8921088u
#define OFF_AQ     10526720u   // 2,007,040
#define OFF_AQ2    12533760u
#define OFF_RVT    14540800u   // 640*4*64*64*2 = 20,971,520
#define OFF_OUT1   35512320u   // 1568*512 bf16 = 1,605,632
#define OFF_P      37117952u   // 640*196*64 bf16 = 16,056,320 -> end 53,174,272

typedef __attribute__((ext_vector_type(8))) short bf16x8;
typedef __attribute__((ext_vector_type(4))) float f32x4;
#define MFMA(a, b, c) __builtin_amdgcn_mfma_f32_16x16x32_bf16((a), (b), (c), 0, 0, 0)

__device__ __forceinline__ unsigned short f2bf(float x) {
  unsigned u = __builtin_bit_cast(unsigned, x);
  u += 0x7fffu + ((u >> 16) & 1u);
  return (unsigned short)(u >> 16);
}
__device__ __forceinline__ float bf2f(unsigned short s) {
  return __builtin_bit_cast(float, ((unsigned)s) << 16);
}

__device__ __forceinline__ void gl_lds16(const void* g, void* l) {
  __builtin_amdgcn_global_load_lds(
      (const __attribute__((address_space(1))) unsigned int*)g,
      (__attribute__((address_space(3))) unsigned int*)l, 16, 0, 0);
}

// Stage a 64x64 bf16 tile (row stride `stride` shorts) into LDS [64][72] via
// global_load_lds. Rows >= nrows skipped (caller pre-zeroes if zeros required).
__device__ __forceinline__ void stage64(const unsigned short* g0, int stride,
                                        unsigned short (*T)[72], int tid, int nrows) {
  int wv = tid >> 6;
  char* base = (char*)&T[0][0];
#pragma unroll
  for (int i = 0; i < 2; i++) {
    int k = i * 256 + tid;
    int r = k / 9, c = k - r * 9;
    if (r < nrows)
      gl_lds16(g0 + (size_t)r * stride + (c << 3), base + (((i << 2) + wv) << 10));
  }
  if (tid < 64) {
    int k = 512 + tid;
    int r = k / 9, c = k - r * 9;
    if (r < nrows)
      gl_lds16(g0 + (size_t)r * stride + (c << 3), base + 8192);
  }
}

// Stage a 64x64 A-tile from fp32 source with on-the-fly bf16 conversion.
// Rows >= M are zeroed (also prevents OOB reads of the input buffer).
__device__ __forceinline__ void stageA_f32(unsigned short (*T)[72], const float* __restrict__ A,
                                           int row0, int M, int k0, int tid) {
  int r = tid >> 2, cs = (tid & 3) << 4;
  float4 f0 = make_float4(0.f, 0.f, 0.f, 0.f), f1 = f0, f2 = f0, f3 = f0;
  if (row0 + r < M) {
    const float* p = A + (size_t)(row0 + r) * 512 + k0 + cs;
    f0 = *(const float4*)p;
    f1 = *(const float4*)(p + 4);
    f2 = *(const float4*)(p + 8);
    f3 = *(const float4*)(p + 12);
  }
  unsigned short s[16] = {f2bf(f0.x), f2bf(f0.y), f2bf(f0.z), f2bf(f0.w),
                          f2bf(f1.x), f2bf(f1.y), f2bf(f1.z), f2bf(f1.w),
                          f2bf(f2.x), f2bf(f2.y), f2bf(f2.z), f2bf(f2.w),
                          f2bf(f3.x), f2bf(f3.y), f2bf(f3.z), f2bf(f3.w)};
  *(uint4*)&T[r][cs] = *(uint4*)s;
  *(uint4*)&T[r][cs + 8] = *(uint4*)(s + 8);
}

// V-transpose load split: issue global loads early (regs), write LDS late.
__device__ __forceinline__ void vload_T(uint4* va, uint4* vb, const unsigned short* __restrict__ g,
                                        int row0, int nrows, int col0, int tid) {
  int j0 = tid >> 3, d0 = (tid & 7) << 3;
  *va = make_uint4(0, 0, 0, 0);
  *vb = make_uint4(0, 0, 0, 0);
  if (j0 < nrows) *va = *(const uint4*)(g + (size_t)(row0 + j0) * 512 + col0 + d0);
  if (j0 + 32 < nrows) *vb = *(const uint4*)(g + (size_t)(row0 + j0 + 32) * 512 + col0 + d0);
}
// XOR-swizzled store: logical Vt[d][j] lives at physical col j ^ ((d>>3)<<3).
// Breaks the 8-way bank alias between rows 8 apart (stride 144B: 8*36 words = 0 mod 32).
__device__ __forceinline__ void vwrite_T(unsigned short T[64][72], uint4 va, uint4 vb, int tid) {
  int j0 = tid >> 3, d0 = (tid & 7) << 3;
  int sw = (tid & 7) << 3;  // (d>>3)<<3 for all 8 rows this lane writes
  unsigned short s[8];
  *(uint4*)s = va;
#pragma unroll
  for (int u = 0; u < 8; u++) T[d0 + u][j0 ^ sw] = s[u];
  *(uint4*)s = vb;
#pragma unroll
  for (int u = 0; u < 8; u++) T[d0 + u][(j0 + 32) ^ sw] = s[u];
}

// ---- pre: W transposes only (x/anchors conversion folded into proj_combo) ----
__global__ __launch_bounds__(256) void pre_kernel(const float* __restrict__ Wqk, const float* __restrict__ Wqk2,
                                                  const float* __restrict__ Wv, const float* __restrict__ Wproj,
                                                  char* __restrict__ ws) {
  __shared__ __align__(16) unsigned short Ls[64][72];
  int tid = threadIdx.x;
  int idx = blockIdx.x;
  int wsel = idx >> 6, t = idx & 63;
  int k0 = (t >> 3) << 6, n0 = (t & 7) << 6;
  const float* W;
  unsigned short* WT;
  switch (wsel) {
    case 0:  W = Wqk;   WT = (unsigned short*)(ws + OFF_WQKT);   break;
    case 1:  W = Wqk2;  WT = (unsigned short*)(ws + OFF_WQK2T);  break;
    case 2:  W = Wv;    WT = (unsigned short*)(ws + OFF_WVT);    break;
    default: W = Wproj; WT = (unsigned short*)(ws + OFF_WPROJT); break;
  }
  {  // load [k][n] tile, convert
    int r = tid >> 2, seg = (tid & 3) << 4;
    const float* p = W + (size_t)(k0 + r) * 512 + n0 + seg;
    float4 f0 = *(const float4*)p, f1 = *(const float4*)(p + 4);
    float4 f2 = *(const float4*)(p + 8), f3 = *(const float4*)(p + 12);
    unsigned short s[16] = {f2bf(f0.x), f2bf(f0.y), f2bf(f0.z), f2bf(f0.w),
                            f2bf(f1.x), f2bf(f1.y), f2bf(f1.z), f2bf(f1.w),
                            f2bf(f2.x), f2bf(f2.y), f2bf(f2.z), f2bf(f2.w),
                            f2bf(f3.x), f2bf(f3.y), f2bf(f3.z), f2bf(f3.w)};
    *(uint4*)&Ls[r][seg] = *(uint4*)s;
    *(uint4*)&Ls[r][seg + 8] = *(uint4*)(s + 8);
  }
  __syncthreads();
  {  // write transposed rows [n][k]
    int r = tid >> 2, seg = (tid & 3) << 4;
    unsigned short s[16];
#pragma unroll
    for (int u = 0; u < 16; u++) s[u] = Ls[seg + u][r];
    unsigned short* dst = WT + (size_t)(n0 + r) * 512 + k0 + seg;
    *(uint4*)dst = *(uint4*)s;
    *(uint4*)(dst + 8) = *(uint4*)(s + 8);
  }
}

// ---- proj_combo: NW outputs sharing one A staging (A converted fp32->bf16 in-stage) ----
template <int NW>
__device__ __forceinline__ void proj_body(const float* __restrict__ A,
                                          const unsigned short* W0, const unsigned short* W1,
                                          const unsigned short* W2,
                                          unsigned short* O0, unsigned short* O1, unsigned short* O2,
                                          int M, unsigned short (*As)[72], unsigned short (*Wsh)[72]) {
  int row0 = (int)blockIdx.x << 6;
  if (row0 >= M) return;
  int col0 = (int)blockIdx.y << 6;
  int tid = threadIdx.x;
  int w = tid >> 6, lm = tid & 15, lq = (tid >> 4) & 3;
  const unsigned short* WTs[3] = {W0, W1, W2};
  unsigned short* Os[3] = {O0, O1, O2};
  f32x4 acc[NW][4] = {};
  for (int k0 = 0; k0 < 512; k0 += 64) {
    __syncthreads();
    stageA_f32(As, A, row0, M, k0, tid);
#pragma unroll
    for (int ww = 0; ww < NW; ww++)
      stage64(WTs[ww] + (size_t)col0 * 512 + k0, 512,
              (unsigned short(*)[72])&Wsh[ww << 6], tid, 64);
    __syncthreads();
#pragma unroll
    for (int kk = 0; kk < 2; kk++) {
      bf16x8 af[4];
#pragma unroll
      for (int mi = 0; mi < 4; mi++)
        af[mi] = *(const bf16x8*)&As[(mi << 4) + lm][(kk << 5) + (lq << 3)];
#pragma unroll
      for (int ww = 0; ww < NW; ww++) {
        bf16x8 bf = *(const bf16x8*)&Wsh[(ww << 6) + (w << 4) + lm][(kk << 5) + (lq << 3)];
#pragma unroll
        for (int mi = 0; mi < 4; mi++) acc[ww][mi] = MFMA(af[mi], bf, acc[ww][mi]);
      }
    }
  }
  int ncol = col0 + (w << 4) + lm;
#pragma unroll
  for (int ww = 0; ww < NW; ww++)
#pragma unroll
    for (int mi = 0; mi < 4; mi++)
#pragma unroll
      for (int r2 = 0; r2 < 4; r2++) {
        int row = row0 + (mi << 4) + (lq << 2) + r2;
        if (row < M)
          Os[ww][(size_t)row * 512 + ncol] = f2bf(acc[ww][mi][r2]);
      }
}

__global__ __launch_bounds__(256) void proj_combo(const float* __restrict__ x,
                                                  const float* __restrict__ anchors,
                                                  char* __restrict__ ws) {
  __shared__ __align__(16) unsigned short As[64][72];
  __shared__ __align__(16) unsigned short Wsh[192][72];
  const unsigned short* wqkt  = (const unsigned short*)(ws + OFF_WQKT);
  const unsigned short* wqk2t = (const unsigned short*)(ws + OFF_WQK2T);
  const unsigned short* wvt   = (const unsigned short*)(ws + OFF_WVT);
  if (blockIdx.z == 0)
    proj_body<3>(x, wqkt, wqk2t, wvt,
                 (unsigned short*)(ws + OFF_XQ), (unsigned short*)(ws + OFF_XQ2),
                 (unsigned short*)(ws + OFF_XV), 1568, As, Wsh);
  else
    proj_body<2>(anchors, wqkt, wqk2t, nullptr,
                 (unsigned short*)(ws + OFF_AQ), (unsigned short*)(ws + OFF_AQ2),
                 nullptr, 1960, As, Wsh);
}

// ---- final GEMM: out[1568,512] = out1 @ WprojT^T + bias (f32) ----
__global__ __launch_bounds__(256) void final_gemm(const unsigned short* __restrict__ out1,
                                                  const unsigned short* __restrict__ WT,
                                                  const float* __restrict__ bias, float* __restrict__ out) {
  __shared__ __align__(16) unsigned short As[64][72];
  __shared__ __align__(16) unsigned short Ws[64][72];
  int row0 = (int)blockIdx.x << 6;
  int col0 = (int)blockIdx.y << 6;
  int tid = threadIdx.x;
  int w = tid >> 6, lm = tid & 15, lq = (tid >> 4) & 3;
  f32x4 acc[4] = {};
  for (int k0 = 0; k0 < 512; k0 += 64) {
    __syncthreads();
    stage64(out1 + (size_t)row0 * 512 + k0, 512, As, tid, 64);  // rows>1568 read ws slack, masked below
    stage64(WT + (size_t)col0 * 512 + k0, 512, Ws, tid, 64);
    __syncthreads();
#pragma unroll
    for (int kk = 0; kk < 2; kk++) {
      bf16x8 bf = *(const bf16x8*)&Ws[(w << 4) + lm][(kk << 5) + (lq << 3)];
#pragma unroll
      for (int mi = 0; mi < 4; mi++) {
        bf16x8 af = *(const bf16x8*)&As[(mi << 4) + lm][(kk << 5) + (lq << 3)];
        acc[mi] = MFMA(af, bf, acc[mi]);
      }
    }
  }
  int ncol = col0 + (w << 4) + lm;
  float bv = bias[ncol];
#pragma unroll
  for (int mi = 0; mi < 4; mi++)
#pragma unroll
    for (int r2 = 0; r2 < 4; r2++) {
      int row = row0 + (mi << 4) + (lq << 2) + r2;
      if (row < 1568)
        out[(size_t)row * 512 + ncol] = acc[mi][r2] + bv;
    }
}

// ---- rv: rvt[bch][it][dd][i=64] = (relu(0.125 * k2 @ q2^T) @ v)^T ----
// Swapped QK. kb direct global->reg (once per block); Qs staged via DMA with
// one-iteration prefetch (R9 lesson). Vt XOR-swizzled. LDS = Qs+Vt+Ss (27,648B).
// XCD-grouped swizzle by (b,h) for xq2/xv L2 reuse.
__global__ __launch_bounds__(256) void rv_mfma(char* __restrict__ ws) {
  const unsigned short* xq2 = (const unsigned short*)(ws + OFF_XQ2);
  const unsigned short* aq2 = (const unsigned short*)(ws + OFF_AQ2);
  const unsigned short* xv  = (const unsigned short*)(ws + OFF_XV);
  unsigned short* rvt       = (unsigned short*)(ws + OFF_RVT);
  __shared__ __align__(16) unsigned short Qs[64][72];  // x (j)
  __shared__ __align__(16) unsigned short Vt[64][72];  // Vt[dd][j], zero-padded, XOR-swizzled
  __shared__ __align__(16) unsigned short Ss[64][72];  // S[i][j]
  // d%8 ~ XCD; wk chunks of 320 works stay on one XCD; wk = (bh*10+c)*4 + it
  int d = blockIdx.x;
  int wk = ((d & 7) * 320) + (d >> 3);
  int it = wk & 3;
  int g = wk >> 2;
  int bh = g / 10, c = g - bh * 10;
  int b = bh >> 3, h = bh & 7;
  int bch = (b * 10 + c) * 8 + h;
  int i0 = it << 6;
  int tid = threadIdx.x;
  int w = tid >> 6, lm = tid & 15, lq = (tid >> 4) & 3;
  int iglob = i0 + (w << 4) + lm;

  // kb direct from global; zero for invalid anchor rows (preserves rvt zero-pad invariant)
  bf16x8 kb[2] = {};
  if (iglob < 196) {
    const unsigned short* kp = aq2 + (size_t)(c * 196 + iglob) * 512 + (h << 6) + (lq << 3);
    kb[0] = *(const bf16x8*)kp;
    kb[1] = *(const bf16x8*)(kp + 32);
  }
  stage64(xq2 + (size_t)(b * 196) * 512 + (h << 6), 512, Qs, tid, 64);
  uint4 va, vb;
  vload_T(&va, &vb, xv, b * 196, 64, h << 6, tid);

  f32x4 acc[4] = {};
#pragma unroll
  for (int jt = 0; jt < 4; jt++) {
    int j0 = jt << 6;
    __syncthreads();  // drains Qs DMA; prev PV done with Ss/Vt
    vwrite_T(Vt, va, vb, tid);
    // QK^T swapped: D[m=j][n=i]
    f32x4 s[4] = {};
#pragma unroll
    for (int kk = 0; kk < 2; kk++)
#pragma unroll
      for (int mj = 0; mj < 4; mj++) {
        bf16x8 af = *(const bf16x8*)&Qs[(mj << 4) + lm][(kk << 5) + (lq << 3)];
        s[mj] = MFMA(af, kb[kk], s[mj]);
      }
#pragma unroll
    for (int mj = 0; mj < 4; mj++) {  // Ss[i = w*16+lm][j runs of 4]
      unsigned short u[4] = {f2bf(fmaxf(0.125f * s[mj][0], 0.f)), f2bf(fmaxf(0.125f * s[mj][1], 0.f)),
                             f2bf(fmaxf(0.125f * s[mj][2], 0.f)), f2bf(fmaxf(0.125f * s[mj][3], 0.f))};
      *(uint2*)&Ss[(w << 4) + lm][(mj << 4) + (lq << 2)] = *(uint2*)u;
    }
    if (jt < 3) vload_T(&va, &vb, xv, b * 196 + j0 + 64, min(64, 196 - j0 - 64), h << 6, tid);
    __syncthreads();
    if (jt < 3) stage64(xq2 + (size_t)(b * 196 + j0 + 64) * 512 + (h << 6), 512, Qs, tid, 64);
    // PV: acc[mi] = R[i][dd]; Vt read through the same XOR swizzle
    int vrow = (w << 4) + lm;
    int vsw = ((vrow >> 3) & 7) << 3;
#pragma unroll
    for (int kk = 0; kk < 2; kk++) {
      bf16x8 bf = *(const bf16x8*)&Vt[vrow][((kk << 5) + (lq << 3)) ^ vsw];
#pragma unroll
      for (int mi = 0; mi < 4; mi++) {
        bf16x8 af = *(const bf16x8*)&Ss[(mi << 4) + lm][(kk << 5) + (lq << 3)];
        acc[mi] = MFMA(af, bf, acc[mi]);
      }
    }
  }
  __syncthreads();
#pragma unroll
  for (int mi = 0; mi < 4; mi++) {  // transpose: Ss[dd][i runs of 4] (vectorized)
    unsigned short u[4] = {f2bf(acc[mi][0]), f2bf(acc[mi][1]), f2bf(acc[mi][2]), f2bf(acc[mi][3])};
    *(uint2*)&Ss[(w << 4) + lm][(mi << 4) + (lq << 2)] = *(uint2*)u;
  }
  __syncthreads();
  {  // rvt block [bch*4+it][dd][64]; rows i>=196 are zeros (kb zeroed)
    int dd = tid >> 2, seg = (tid & 3) << 4;
    unsigned short* dst = rvt + ((size_t)(bch * 4 + it) * 64 + dd) * 64 + seg;
    *(uint4*)dst = *(uint4*)&Ss[dd][seg];
    *(uint4*)(dst + 8) = *(uint4*)&Ss[dd][seg + 8];
  }
}

// ---- attn: left = relu(-0.125*q@k^T) (cached f32x4); P = left @ rv (bf16) ----
// R8 structure: staged Ks DMA w/ prefetch-during-PV; qb + rv direct global->reg.
// LDS = Ks+Ss (18,432B). XCD-grouped swizzle.
__global__ __launch_bounds__(256) void attn_mfma(char* __restrict__ ws, float* __restrict__ left,
                                                 unsigned short* __restrict__ P) {
  const unsigned short* xq  = (const unsigned short*)(ws + OFF_XQ);
  const unsigned short* aq  = (const unsigned short*)(ws + OFF_AQ);
  const unsigned short* rvt = (const unsigned short*)(ws + OFF_RVT);
  __shared__ __align__(16) unsigned short Ks[64][72];  // anchors (j), zero-padded for jt=3
  __shared__ __align__(16) unsigned short Ss[64][72];  // S[i][j]
  int d = blockIdx.x;
  int wk = ((d & 7) * 320) + (d >> 3);
  int i0 = (wk & 3) << 6;
  int g = wk >> 2;                 // g = c*64 + bh
  int c = g >> 6;
  int bh = g & 63;
  int b = bh >> 3, h = bh & 7;
  int bch = (b * 10 + c) * 8 + h;
  int tid = threadIdx.x;
  int w = tid >> 6, lm = tid & 15, lq = (tid >> 4) & 3;
  int iglob = i0 + (w << 4) + lm;

  // qb direct from global (lane's own row; garbage rows ok - stores masked; stays in ws)
  bf16x8 qb[2];
  {
    const unsigned short* qp = xq + (size_t)(b * 196 + iglob) * 512 + (h << 6) + (lq << 3);
    qb[0] = *(const bf16x8*)qp;
    qb[1] = *(const bf16x8*)(qp + 32);
  }
  {  // zero Ks rows 4..63 once; stage jt=3's 4 valid rows
    uint4 z = make_uint4(0, 0, 0, 0);
    for (int k = tid; k < 540; k += 256)
      *(uint4*)((char*)&Ks[0][0] + 576 + k * 16) = z;
  }
  stage64(aq + (size_t)(c * 196 + 192) * 512 + (h << 6), 512, Ks, tid, 4);
  // rv fragment prefetch for t=0 (jt=3)
  const unsigned short* rbase = rvt + (size_t)bch * 16384 + (((w << 4) + lm) << 6) + (lq << 3);
  bf16x8 rv0 = *(const bf16x8*)(rbase + 3 * 4096);
  bf16x8 rv1 = *(const bf16x8*)(rbase + 3 * 4096 + 32);

  f32x4 acc[4] = {};
  size_t lbase = (size_t)bch * (196 * 196);
  // jt order {3,0,1,2}: jt=3 first against pre-zeroed rows; others overwrite fully.
#pragma unroll
  for (int t = 0; t < 4; t++) {
    int jt = (t == 0) ? 3 : t - 1;
    int j0 = jt << 6;
    __syncthreads();  // Ks ready (DMA drained); prev PV done with Ss
    // QK^T swapped: D[m=j][n=i]
    f32x4 s[4] = {};
#pragma unroll
    for (int kk = 0; kk < 2; kk++)
#pragma unroll
      for (int mj = 0; mj < 4; mj++) {
        bf16x8 af = *(const bf16x8*)&Ks[(mj << 4) + lm][(kk << 5) + (lq << 3)];
        s[mj] = MFMA(af, qb[kk], s[mj]);
      }
#pragma unroll
    for (int mj = 0; mj < 4; mj++) {
      f32x4 lv;
      lv[0] = fmaxf(-0.125f * s[mj][0], 0.f);
      lv[1] = fmaxf(-0.125f * s[mj][1], 0.f);
      lv[2] = fmaxf(-0.125f * s[mj][2], 0.f);
      lv[3] = fmaxf(-0.125f * s[mj][3], 0.f);
      int jloc = (mj << 4) + (lq << 2);
      if (iglob < 196 && j0 + jloc < 196)   // runs never straddle 196 (196%4==0)
        *(f32x4*)&left[lbase + (size_t)iglob * 196 + j0 + jloc] = lv;
      unsigned short u[4] = {f2bf(lv[0]), f2bf(lv[1]), f2bf(lv[2]), f2bf(lv[3])};
      *(uint2*)&Ss[(w << 4) + lm][jloc] = *(uint2*)u;
    }
    __syncthreads();
    if (t < 3)  // next jt = t: stage during PV, drained at next barrier
      stage64(aq + (size_t)(c * 196 + (t << 6)) * 512 + (h << 6), 512, Ks, tid, 64);
    bf16x8 cur0 = rv0, cur1 = rv1;
    if (t < 3) {  // prefetch next rv tile (jt = t), consumed next iteration
      rv0 = *(const bf16x8*)(rbase + t * 4096);
      rv1 = *(const bf16x8*)(rbase + t * 4096 + 32);
    }
    // PV: acc[mi] = P[i][dd]
#pragma unroll
    for (int kk = 0; kk < 2; kk++) {
      bf16x8 bf = (kk == 0) ? cur0 : cur1;
#pragma unroll
      for (int mi = 0; mi < 4; mi++) {
        bf16x8 af = *(const bf16x8*)&Ss[(mi << 4) + lm][(kk << 5) + (lq << 3)];
        acc[mi] = MFMA(af, bf, acc[mi]);
      }
    }
  }
  __syncthreads();
#pragma unroll
  for (int mi = 0; mi < 4; mi++)   // P tile transpose into Ss[i][dd]
#pragma unroll
    for (int r = 0; r < 4; r++)
      Ss[(mi << 4) + (lq << 2) + r][(w << 4) + lm] = f2bf(acc[mi][r]);
  __syncthreads();
  {
    int row = tid >> 2, seg = (tid & 3) << 4;
    if (i0 + row < 196) {
      unsigned short* dst = P + ((size_t)(bh * 10 + c) * 196 + i0 + row) * 64 + seg;
      *(uint4*)dst = *(uint4*)&Ss[row][seg];
      *(uint4*)(dst + 8) = *(uint4*)&Ss[row][seg + 8];
    }
  }
}

// ---- out1[bh][n][dd] = sum_c weights[bh,c] * P[bh][c][n][dd]  (bf16 out) ----
__global__ __launch_bounds__(256) void reduce_out1(const unsigned short* __restrict__ P,
                                                   const float* __restrict__ weights,
                                                   unsigned short* __restrict__ out1) {
  int t = blockIdx.x * 256 + threadIdx.x;
  int base = t << 2;
  int bh = base / 12544;
  int rem = base - bh * 12544;
  const float* wrow = weights + bh * 10;
  float a0 = 0.f, a1 = 0.f, a2 = 0.f, a3 = 0.f;
#pragma unroll
  for (int c = 0; c < 10; c++) {
    float wc = wrow[c];
    const unsigned short* p = P + ((size_t)(bh * 10 + c)) * 12544 + rem;
    ushort4 u = *(const ushort4*)p;
    a0 = fmaf(wc, bf2f(u.x), a0);
    a1 = fmaf(wc, bf2f(u.y), a1);
    a2 = fmaf(wc, bf2f(u.z), a2);
    a3 = fmaf(wc, bf2f(u.w), a3);
  }
  unsigned short s[4] = {f2bf(a0), f2bf(a1), f2bf(a2), f2bf(a3)};
  *(uint2*)&out1[base] = *(uint2*)s;
}

extern "C" void kernel_launch(void* const* d_in, const int* in_sizes, int n_in,
                              void* d_out, int out_size, void* d_ws, size_t ws_size,
                              hipStream_t stream) {
  (void)in_sizes; (void)n_in; (void)out_size; (void)ws_size;
  const float* x       = (const float*)d_in[0];
  const float* anchors = (const float*)d_in[1];
  const float* weights = (const float*)d_in[2];
  const float* Wqk     = (const float*)d_in[3];
  const float* Wqk2    = (const float*)d_in[4];
  const float* Wv      = (const float*)d_in[5];
  const float* Wproj   = (const float*)d_in[6];
  const float* bproj   = (const float*)d_in[7];
  char* ws = (char*)d_ws;
  float* out  = (float*)d_out;
  float* left = out + 802816;

  dim3 blk(256);
  pre_kernel<<<dim3(256), blk, 0, stream>>>(Wqk, Wqk2, Wv, Wproj, ws);
  proj_combo<<<dim3(31, 8, 2), blk, 0, stream>>>(x, anchors, ws);
  rv_mfma<<<dim3(2560), blk, 0, stream>>>(ws);
  attn_mfma<<<dim3(2560), blk, 0, stream>>>(ws, left, (unsigned short*)(ws + OFF_P));
  reduce_out1<<<dim3(784), blk, 0, stream>>>((const unsigned short*)(ws + OFF_P), weights,
                                             (unsigned short*)(ws + OFF_OUT1));
  final_gemm<<<dim3(25, 8), blk, 0, stream>>>((const unsigned short*)(ws + OFF_OUT1),
                                              (const unsigned short*)(ws + OFF_WPROJT), bproj, out);
}